// Round 5
// baseline (26.151 us; speedup 1.0000x reference)
//
#include <hip/hip_runtime.h>

// L_x1 L_x2 of RBF kernel k(x1,x2)=exp(-||x1-x2||^2/(2 l^2)) in D=2.
// Closed form: with a = 1/l^2, s = ||x1-x2||^2:
//   L_x1 L_x2 k = exp(-0.5*a*s) * (a^4 s^2 - 8 a^3 s + 8 a^2)
//
// ROUND 5 = SLOPE DIAGNOSTIC: same as round-3 kernel (best, 16.79 us), but
// optionally duplicates every output store into d_ws (exactly 2x write
// traffic, same compute, one dispatch). Delta(dur) measures marginal write
// bandwidth: +10 us -> 6.5 TB/s (already at roofline, rest is fixed
// overhead); +17 us -> 3.8 TB/s steady (real problem to attack).

#define N1 4096
#define N2 4096
#define ROWS_PER_BLOCK 4
#define GROUPS 4  // float4 output groups per thread per row (4*256*4 = 4096 cols)

typedef float v4f __attribute__((ext_vector_type(4)));

__device__ __forceinline__ float pair_val(float x10, float x11, float px, float py,
                                          float ce, float c4, float c3n, float c2) {
    float d0 = x10 - px, d1 = x11 - py;
    float s = fmaf(d1, d1, d0 * d0);
    float poly = fmaf(s, fmaf(s, c4, c3n), c2);  // c4*s^2 + c3n*s + c2
    return __expf(ce * s) * poly;
}

template <bool DUP>
__global__ __launch_bounds__(256) void poisson_lxlx_kernel(
    const float* __restrict__ X1, const float* __restrict__ X2,
    const float* __restrict__ ls, float* __restrict__ out,
    float* __restrict__ ws)
{
    const int t  = threadIdx.x;
    const int i0 = blockIdx.x * ROWS_PER_BLOCK;

    const float l  = ls[0];
    const float a  = 1.0f / (l * l);
    const float a2 = a * a;
    const float c4  = a2 * a2;
    const float c3n = -8.0f * a2 * a;
    const float c2  = 8.0f * a2;
    const float ce  = -0.5f * a;

    // Cache this thread's X2 points in registers: GROUPS groups of 4 points.
    v4f xa[GROUPS], xb[GROUPS];
#pragma unroll
    for (int g = 0; g < GROUPS; ++g) {
        const int col4 = g * 256 + t;                 // float4-group index in row
        const float* p = X2 + (size_t)col4 * 8;       // 4 points = 8 floats
        xa[g] = *reinterpret_cast<const v4f*>(p);
        xb[g] = *reinterpret_cast<const v4f*>(p + 4);
    }

#pragma unroll
    for (int r = 0; r < ROWS_PER_BLOCK; ++r) {
        const int i = i0 + r;
        const float x10 = X1[2 * i];
        const float x11 = X1[2 * i + 1];
        float* rowp = out + (size_t)i * N2;
        float* wsp  = ws  + (size_t)i * N2;
#pragma unroll
        for (int g = 0; g < GROUPS; ++g) {
            v4f res;
            res.x = pair_val(x10, x11, xa[g].x, xa[g].y, ce, c4, c3n, c2);
            res.y = pair_val(x10, x11, xa[g].z, xa[g].w, ce, c4, c3n, c2);
            res.z = pair_val(x10, x11, xb[g].x, xb[g].y, ce, c4, c3n, c2);
            res.w = pair_val(x10, x11, xb[g].z, xb[g].w, ce, c4, c3n, c2);
            const int col4 = g * 256 + t;
            *reinterpret_cast<v4f*>(rowp + (size_t)col4 * 4) = res;
            if (DUP) {
                *reinterpret_cast<v4f*>(wsp + (size_t)col4 * 4) = res;
            }
        }
    }
}

extern "C" void kernel_launch(void* const* d_in, const int* in_sizes, int n_in,
                              void* d_out, int out_size, void* d_ws, size_t ws_size,
                              hipStream_t stream) {
    const float* X1 = (const float*)d_in[0];
    const float* X2 = (const float*)d_in[1];
    const float* ls = (const float*)d_in[2];
    float* out = (float*)d_out;
    float* ws  = (float*)d_ws;

    dim3 block(256);
    dim3 grid(N1 / ROWS_PER_BLOCK);  // 1024 blocks

    const bool dup = ws_size >= (size_t)N1 * N2 * sizeof(float);
    if (dup) {
        poisson_lxlx_kernel<true><<<grid, block, 0, stream>>>(X1, X2, ls, out, ws);
    } else {
        poisson_lxlx_kernel<false><<<grid, block, 0, stream>>>(X1, X2, ls, out, ws);
    }
}

// Round 6
// 16.721 us; speedup vs baseline: 1.5639x; 1.5639x over previous
//
#include <hip/hip_runtime.h>

// L_x1 L_x2 of RBF kernel k(x1,x2)=exp(-||x1-x2||^2/(2 l^2)) in D=2.
// Closed form: with a = 1/l^2, s = ||x1-x2||^2:
//   L_x1 L_x2 k = exp(-0.5*a*s) * (a^4 s^2 - 8 a^3 s + 8 a^2)
//
// FINAL (round-3 structure): 1024 blocks x 256 threads, 4 rows/block,
// X2 cached in registers across rows, lane-contiguous float4 stores
// (1 KB per wave-store-instruction). Measured 16.79 us.
//
// Roofline evidence (round-5 slope diagnostic): duplicating all stores into
// d_ws (+64 MB) cost +9.36 us -> marginal write BW ~6.9 TB/s = achievable
// HBM ceiling. Base time = ~9.5 us writes + ~7 us traffic-invariant
// dispatch/ramp overhead. nt-stores (round 4) and wave-shape (rounds 1/3)
// are null; compute (~2 us VALU) hides under stores. Output is 64 MB fp32,
// mandatory -> nothing left to win at kernel-source level.

#define N1 4096
#define N2 4096
#define ROWS_PER_BLOCK 4
#define GROUPS 4  // float4 output groups per thread per row (4*256*4 = 4096 cols)

typedef float v4f __attribute__((ext_vector_type(4)));

__device__ __forceinline__ float pair_val(float x10, float x11, float px, float py,
                                          float ce, float c4, float c3n, float c2) {
    float d0 = x10 - px, d1 = x11 - py;
    float s = fmaf(d1, d1, d0 * d0);
    float poly = fmaf(s, fmaf(s, c4, c3n), c2);  // c4*s^2 + c3n*s + c2
    return __expf(ce * s) * poly;
}

__global__ __launch_bounds__(256) void poisson_lxlx_kernel(
    const float* __restrict__ X1, const float* __restrict__ X2,
    const float* __restrict__ ls, float* __restrict__ out)
{
    const int t  = threadIdx.x;
    const int i0 = blockIdx.x * ROWS_PER_BLOCK;

    const float l  = ls[0];
    const float a  = 1.0f / (l * l);
    const float a2 = a * a;
    const float c4  = a2 * a2;
    const float c3n = -8.0f * a2 * a;
    const float c2  = 8.0f * a2;
    const float ce  = -0.5f * a;

    // Cache this thread's X2 points in registers: GROUPS groups of 4 points.
    v4f xa[GROUPS], xb[GROUPS];
#pragma unroll
    for (int g = 0; g < GROUPS; ++g) {
        const int col4 = g * 256 + t;                 // float4-group index in row
        const float* p = X2 + (size_t)col4 * 8;       // 4 points = 8 floats
        xa[g] = *reinterpret_cast<const v4f*>(p);
        xb[g] = *reinterpret_cast<const v4f*>(p + 4);
    }

#pragma unroll
    for (int r = 0; r < ROWS_PER_BLOCK; ++r) {
        const int i = i0 + r;
        const float x10 = X1[2 * i];
        const float x11 = X1[2 * i + 1];
        float* rowp = out + (size_t)i * N2;
#pragma unroll
        for (int g = 0; g < GROUPS; ++g) {
            v4f res;
            res.x = pair_val(x10, x11, xa[g].x, xa[g].y, ce, c4, c3n, c2);
            res.y = pair_val(x10, x11, xa[g].z, xa[g].w, ce, c4, c3n, c2);
            res.z = pair_val(x10, x11, xb[g].x, xb[g].y, ce, c4, c3n, c2);
            res.w = pair_val(x10, x11, xb[g].z, xb[g].w, ce, c4, c3n, c2);
            const int col4 = g * 256 + t;
            *reinterpret_cast<v4f*>(rowp + (size_t)col4 * 4) = res;
        }
    }
}

extern "C" void kernel_launch(void* const* d_in, const int* in_sizes, int n_in,
                              void* d_out, int out_size, void* d_ws, size_t ws_size,
                              hipStream_t stream) {
    const float* X1 = (const float*)d_in[0];
    const float* X2 = (const float*)d_in[1];
    const float* ls = (const float*)d_in[2];
    float* out = (float*)d_out;

    dim3 block(256);
    dim3 grid(N1 / ROWS_PER_BLOCK);  // 1024 blocks
    poisson_lxlx_kernel<<<grid, block, 0, stream>>>(X1, X2, ls, out);
}